// Round 11
// baseline (6571.102 us; speedup 1.0000x reference)
//
#include <hip/hip_runtime.h>

// CustomLSTM on MI355X: persistent cooperative kernel. R11: TPB=1024 (16 waves,
// 4/SIMD): wave = (layer, row-tile, K-half), each wave computes only its own
// layer's products; kh=1 publishes partial via LDS, kh=0 finalizes. Oct h-ring,
// early acquire-inv at arrival, tree barrier, xg pre-GEMM, Wh pinned (64 VGPR).

#define NBLK 256
#define TPB  1024
#define T_   512
#define HS_OFF 33554432   // outputs floats
#define CS_OFF 33685504   // HS_OFF + 2*64*1024

typedef float  f32x4  __attribute__((ext_vector_type(4)));
typedef short  bf16x8 __attribute__((ext_vector_type(8)));

// ---- workspace byte offsets ----
#define WS_CTR  0u              // 69632: gctr[8][1024] | rctr[1024] | gflag[8][1024]
#define WS_W    69632u          // 4 * (4096*1024) bf16 = 32 MiB (permuted, [m][p][k])
#define WS_BIAS 33624064u       // 2*4096 f32
#define WS_XB   33656832u       // [T][B][D] bf16 = 64 MiB
#define WS_H0   100765696u      // ring: 2 * 65536 bf16, layout [oct][row][8]
#define WS_H1   101027840u
#define WS_MIN  101289984u      // minimum ws (no xg)
#define WS_XG   101289984u      // [T][256][4][64][4] bf16 = 256 MiB
#define WS_BIG  369725440u

__device__ __forceinline__ unsigned short f2bf(float f) {
  union { float f; unsigned u; } v; v.f = f;
  return (unsigned short)((v.u + 0x7FFFu + ((v.u >> 16) & 1u)) >> 16);
}
__device__ __forceinline__ float bf2f(unsigned short s) {
  union { unsigned u; float f; } v; v.u = ((unsigned)s) << 16;
  return v.f;
}
__device__ __forceinline__ float fsig(float x) { return 1.0f / (1.0f + __expf(-x)); }
__device__ __forceinline__ float ftanh(float x) {
  x = fminf(15.0f, fmaxf(-15.0f, x));
  float e = __expf(2.0f * x);
  return (e - 1.0f) / (e + 1.0f);
}

// Permute+transpose+bf16 the 4 weight matrices: out[m][p][k] = bf16(W_m[k][orig(p)]),
// orig(p) = (p&3)*1024 + (p>>2)  (p = 4*j + gate). 64x64 tiles via LDS.
__global__ void kw(const float* __restrict__ Wx0, const float* __restrict__ Wh0,
                   const float* __restrict__ Wx1, const float* __restrict__ Wh1,
                   unsigned short* __restrict__ wp) {
  __shared__ float tile[64][65];
  int tb = blockIdx.x;
  int m  = tb >> 10;
  int kt = (tb >> 6) & 15;
  int nt = tb & 63;
  const float* W = (m == 0) ? Wx0 : (m == 1) ? Wh0 : (m == 2) ? Wx1 : Wh1;
  unsigned short* O = wp + (size_t)m * 4194304u;
  int k0 = kt * 64, n0 = nt * 64;
  int tx = threadIdx.x & 63, tg = threadIdx.x >> 6;
  for (int r = tg; r < 64; r += 4)
    tile[r][tx] = W[(size_t)(k0 + r) * 4096 + n0 + tx];
  __syncthreads();
  for (int r = tg; r < 64; r += 4) {
    int n = n0 + r;
    int p = ((n & 1023) << 2) | (n >> 10);
    O[(size_t)p * 1024 + k0 + tx] = f2bf(tile[tx][r]);
  }
}

// x [B][T][D] f32 -> xb [T*B][D] bf16 (row = t*64+b)
__global__ void kx(const float* __restrict__ x, unsigned short* __restrict__ xb) {
  int row = blockIdx.x;
  int t = row >> 6, b = row & 63;
  const float4* src = (const float4*)(x + ((size_t)b * 512 + t) * 1024);
  float4 f = src[threadIdx.x];
  ushort4 o; o.x = f2bf(f.x); o.y = f2bf(f.y); o.z = f2bf(f.z); o.w = f2bf(f.w);
  ((ushort4*)(xb + (size_t)row * 1024))[threadIdx.x] = o;
}

// bias permute + prime ring slot 1 with initial h states (bf16, [oct][row][8])
__global__ void kmisc(const float* __restrict__ b0, const float* __restrict__ b1,
                      const float* __restrict__ h0in,
                      float* __restrict__ biasP,
                      unsigned short* __restrict__ h0r, unsigned short* __restrict__ h1r) {
  int idx = blockIdx.x * 256 + threadIdx.x;
  if (idx < 8192) {
    int layer = idx >> 12, p = idx & 4095;
    int orig = (p & 3) * 1024 + (p >> 2);
    biasP[idx] = (layer ? b1 : b0)[orig];
  } else if (idx < 139264) {
    int e = idx - 8192;
    int layer = e >> 16, o = e & 65535;
    int row = o >> 10, col = o & 1023;
    unsigned short v = f2bf(h0in[layer * 65536 + o]);
    int dst = 65536 + (col >> 3) * 512 + row * 8 + (col & 7);
    if (layer) h1r[dst] = v; else h0r[dst] = v;
  }
}

// Pre-GEMM: xg[t][cb16][rt][lane][v] = (x[t] @ Wx0) fragment, finalize-lane layout.
__global__ void __launch_bounds__(512, 2)
kxg(const unsigned short* __restrict__ wp, const unsigned short* __restrict__ xb,
    unsigned short* __restrict__ xg) {
  __shared__ char sm[73728];                 // 64KB Wx0 slice + 8KB red
  float* red = (float*)(sm + 65536);
  const int tid = threadIdx.x;
  const int w = tid >> 6, l = tid & 63;
  const int cb = blockIdx.x >> 4;            // 32-col block, 0..127
  const int tc = blockIdx.x & 15;
  const int rt = w & 3, kh = w >> 2;

  const char* src = (const char*)(wp + (size_t)(cb * 32) * 1024u);
  for (int i = tid; i < 4096; i += 512) {
    int sb = i << 4;
    int c  = sb >> 11;
    int kb = sb & 2047;
    *(uint4*)(sm + (c << 11) + (kb ^ ((c & 7) << 4))) = *(const uint4*)(src + sb);
  }
  __syncthreads();

  const int ae0 = (rt * 16 + (l & 15)) * 1024 + kh * 512 + (l >> 4) * 8;
  const int kb2 = kh * 1024 + (l >> 4) * 16;
  const int swz = (l & 7) << 4;
  const int lb0 = (l & 15) << 11;
  const int lb1 = ((l & 15) + 16) << 11;

  for (int t = tc * 32; t < tc * 32 + 32; ++t) {
    const unsigned short* xt = xb + (size_t)t * 65536u;
    f32x4 a0 = {0.f, 0.f, 0.f, 0.f};
    f32x4 a1 = {0.f, 0.f, 0.f, 0.f};
    #pragma unroll
    for (int kk = 0; kk < 16; ++kk) {
      bf16x8 ax = *(const bf16x8*)(xt + ae0 + kk * 32);
      const int kb = (kb2 + kk * 64) ^ swz;
      bf16x8 b0 = *(const bf16x8*)(sm + lb0 + kb);
      bf16x8 b1 = *(const bf16x8*)(sm + lb1 + kb);
      a0 = __builtin_amdgcn_mfma_f32_16x16x32_bf16(ax, b0, a0, 0, 0, 0);
      a1 = __builtin_amdgcn_mfma_f32_16x16x32_bf16(ax, b1, a1, 0, 0, 0);
    }
    if (kh == 1) {
      float* r0 = red + (size_t)((rt * 2 + 0) * 64 + l) * 4;
      float* r1 = red + (size_t)((rt * 2 + 1) * 64 + l) * 4;
      #pragma unroll
      for (int v = 0; v < 4; ++v) { r0[v] = a0[v]; r1[v] = a1[v]; }
    }
    __syncthreads();
    if (kh == 0) {
      const float* r0 = red + (size_t)((rt * 2 + 0) * 64 + l) * 4;
      const float* r1 = red + (size_t)((rt * 2 + 1) * 64 + l) * 4;
      ushort4 o0, o1;
      o0.x = f2bf(a0[0] + r0[0]); o0.y = f2bf(a0[1] + r0[1]);
      o0.z = f2bf(a0[2] + r0[2]); o0.w = f2bf(a0[3] + r0[3]);
      o1.x = f2bf(a1[0] + r1[0]); o1.y = f2bf(a1[1] + r1[1]);
      o1.z = f2bf(a1[2] + r1[2]); o1.w = f2bf(a1[3] + r1[3]);
      *(ushort4*)(xg + ((((size_t)t * 256 + (cb * 2 + 0)) * 4 + rt) * 64 + l) * 4) = o0;
      *(ushort4*)(xg + ((((size_t)t * 256 + (cb * 2 + 1)) * 4 + rt) * 64 + l) * 4) = o1;
    }
    __syncthreads();
  }
}

// Persistent cooperative kernel. 256 blocks x 1024 threads (16 waves, 4/SIMD).
// Wave w: lay = w>>3, rt = (w>>1)&3, kh = w&1. Each wave computes ONLY its
// layer's products for its K-half; kh=1 publishes via LDS, kh=0 finalizes.
__global__ void __launch_bounds__(TPB)
klstm(const float* __restrict__ c0_in,
      const unsigned short* __restrict__ wp,
      const float* __restrict__ biasP,
      const unsigned short* __restrict__ xb,
      const unsigned short* __restrict__ xg,
      unsigned short* __restrict__ h0ring,
      unsigned short* __restrict__ h1ring,
      unsigned* __restrict__ ctrbase,
      float* __restrict__ out,
      int use_xg) {
  extern __shared__ char smem[];           // 32K Wx1 | 32K Wx0(fb) | 8K red | 2K lh
  float* red = (float*)(smem + 65536);
  float* lhb = (float*)(smem + 73728);
  unsigned* gctr  = ctrbase;               // [8][1024]
  unsigned* rctr  = ctrbase + 8192;        // [1024]
  unsigned* gflag = ctrbase + 9216;        // [8][1024]
  const int tid = threadIdx.x;
  const int w   = tid >> 6;
  const int l   = tid & 63;
  const int bid = blockIdx.x;
  const int n0  = bid * 16;
  const int lay = w >> 3;
  const int rt  = (w >> 1) & 3;
  const int kh  = w & 1;
  const int rbase = rt * 16;
  const int khalf = kh * 512;
  const int grp   = bid >> 5;
  const int slot  = lay * 4 + rt;          // exchange/finalize slot
  float* lh = lhb + slot * 64;             // [16 rows][4 cols] f32 per slot

  // stage Wx1 (m=2) at 0; Wx0 (m=0) at 32K only in fallback mode
  {
    const char* src = (const char*)(wp + 2u * 4194304u + (size_t)n0 * 1024u);
    for (int i = tid; i < 2048; i += TPB) {
      int sb = i << 4;
      int c  = sb >> 11;
      int kb = sb & 2047;
      *(uint4*)(smem + (c << 11) + (kb ^ ((c & 7) << 4))) = *(const uint4*)(src + sb);
    }
    if (!use_xg) {
      const char* s0 = (const char*)(wp + (size_t)n0 * 1024u);
      for (int i = tid; i < 2048; i += TPB) {
        int sb = i << 4;
        int c  = sb >> 11;
        int kb = sb & 2047;
        *(uint4*)(smem + 32768 + (c << 11) + (kb ^ ((c & 7) << 4))) = *(const uint4*)(s0 + sb);
      }
    }
  }

  // pin this wave's layer Wh fragments (16 cols x its K-half): 64 VGPR
  bf16x8 whf[16];
  {
    const unsigned short* pw_ = wp + (size_t)(lay ? 3u : 1u) * 4194304u
                              + (size_t)(n0 + (l & 15)) * 1024u + khalf + (l >> 4) * 8;
    #pragma unroll
    for (int ks = 0; ks < 16; ++ks) whf[ks] = *(const bf16x8*)(pw_ + ks * 32);
  }

  const int jg = bid * 4 + ((l & 15) >> 2);   // global h column (gate finalize)
  const float biasv = biasP[lay * 4096 + n0 + (l & 15)];
  const int qb = l & ~3;

  float cr[4] = {0.f, 0.f, 0.f, 0.f};
  if (kh == 0) {
    #pragma unroll
    for (int v = 0; v < 4; ++v)
      cr[v] = c0_in[lay * 65536 + (rbase + (l >> 4) * 4 + v) * 1024 + jg];
  }
  __syncthreads();

  const int ae0  = (rbase + (l & 15)) * 1024 + khalf + (l >> 4) * 8;  // xb (row-major)
  const int hbase = ((khalf >> 3) + (l >> 4)) * 512 + (rbase + (l & 15)) * 8;
  const int lb0  = (l & 15) << 11;
  const int kb2  = khalf * 2 + (l >> 4) * 16;
  const int swz  = (l & 7) << 4;
  const int hsto = (bid >> 1) * 512 + 4 * (bid & 1);

  float xgf[4] = {0.f, 0.f, 0.f, 0.f};
  if (use_xg && lay == 0 && kh == 0) {
    ushort4 xv = *(const ushort4*)(xg + (((size_t)bid * 4 + rt) * 64 + l) * 4);
    xgf[0] = bf2f(xv.x); xgf[1] = bf2f(xv.y); xgf[2] = bf2f(xv.z); xgf[3] = bf2f(xv.w);
  }

  for (int k = 0; k <= T_; ++k) {
    #pragma unroll
    for (int ks = 0; ks < 16; ++ks) asm volatile("" :: "v"(whf[ks]));

    const unsigned short* h0p = h0ring + ((k + 1) & 1) * 65536;
    const unsigned short* h1p = h1ring + (k & 1) * 65536;

    f32x4 accA = {0.f, 0.f, 0.f, 0.f};     // L0: h0@Wh0 | L1: h0@Wx1
    f32x4 accB = {0.f, 0.f, 0.f, 0.f};     // L0: x@Wx0 (fb) | L1: h1@Wh1
    if (lay == 0) {
      #pragma unroll
      for (int kk = 0; kk < 16; ++kk) {
        bf16x8 ah0 = *(const bf16x8*)(h0p + hbase + kk * 2048);
        accA = __builtin_amdgcn_mfma_f32_16x16x32_bf16(ah0, whf[kk], accA, 0, 0, 0);
      }
      if (!use_xg) {
        const unsigned short* xt = xb + (size_t)((k < T_) ? k : (T_ - 1)) * 65536u;
        #pragma unroll
        for (int kk = 0; kk < 16; ++kk) {
          bf16x8 ax  = *(const bf16x8*)(xt + ae0 + kk * 32);
          bf16x8 bx0 = *(const bf16x8*)(smem + 32768 + lb0 + ((kb2 + kk * 64) ^ swz));
          accB = __builtin_amdgcn_mfma_f32_16x16x32_bf16(ax, bx0, accB, 0, 0, 0);
        }
      }
    } else {
      #pragma unroll
      for (int kk = 0; kk < 16; ++kk) {
        bf16x8 ah0 = *(const bf16x8*)(h0p + hbase + kk * 2048);
        bf16x8 ah1 = *(const bf16x8*)(h1p + hbase + kk * 2048);
        bf16x8 bx1 = *(const bf16x8*)(smem + lb0 + ((kb2 + kk * 64) ^ swz));
        accA = __builtin_amdgcn_mfma_f32_16x16x32_bf16(ah0, bx1, accA, 0, 0, 0);
        accB = __builtin_amdgcn_mfma_f32_16x16x32_bf16(ah1, whf[kk], accB, 0, 0, 0);
      }
    }

    if (kh == 1) {   // publish this K-half's partial
      float* rb = red + (size_t)slot * 256 + (size_t)l * 4;
      f32x4 s = accA + accB;
      #pragma unroll
      for (int v = 0; v < 4; ++v) rb[v] = s[v];
    }
    __syncthreads();

    const bool active = lay ? (k >= 1) : (k < T_);
    f32x4 outv = {0.f, 0.f, 0.f, 0.f};
    if (kh == 0 && active) {
      f32x4 g = accA + accB;
      {
        const float* rb = red + (size_t)slot * 256 + (size_t)l * 4;
        #pragma unroll
        for (int v = 0; v < 4; ++v) g[v] += rb[v];
      }
      if (lay == 0) {
        #pragma unroll
        for (int v = 0; v < 4; ++v) g[v] += xgf[v];
      }
      unsigned short* hw = lay ? (h1ring + ((k + 1) & 1) * 65536)
                               : (h0ring + (k & 1) * 65536);
      #pragma unroll
      for (int v = 0; v < 4; ++v) {
        float gv = g[v] + biasv;
        float gi = __shfl(gv, qb);
        float gf = __shfl(gv, qb | 1);
        float gn = __shfl(gv, qb | 2);
        float go = __shfl(gv, qb | 3);
        float i_ = fsig(gi), f_ = fsig(gf), n_ = ftanh(gn), o_ = fsig(go);
        float c = f_ * cr[v] + i_ * n_;
        cr[v] = c;
        float h = o_ * ftanh(c);
        if ((l & 3) == 0)
          lh[((l >> 4) * 4 + v) * 4 + ((l & 15) >> 2)] = h;   // repack tile
      }
      if (l < 16) {   // same-wave read-back: coalesced 8B agent store
        f32x4 h4 = *(f32x4*)(lh + l * 4);
        outv = h4;
        ushort4 u4;
        u4.x = f2bf(h4[0]); u4.y = f2bf(h4[1]); u4.z = f2bf(h4[2]); u4.w = f2bf(h4[3]);
        union { ushort4 s; unsigned long long q; } pk; pk.s = u4;
        __hip_atomic_store((unsigned long long*)(hw + hsto + (rbase + l) * 8), pk.q,
                           __ATOMIC_RELAXED, __HIP_MEMORY_SCOPE_AGENT);
      }
    }

    // ---- barrier arrival + early acquire-inv (off the critical path) ----
    if (k < T_) {
      __syncthreads();                      // drain h stores block-wide
      if (tid == 0) {
        unsigned old = __hip_atomic_fetch_add(&gctr[grp * 1024 + k], 1u,
                                              __ATOMIC_RELAXED, __HIP_MEMORY_SCOPE_AGENT);
        if (old == 31u) {
          unsigned oldr = __hip_atomic_fetch_add(&rctr[k], 1u,
                                                 __ATOMIC_RELAXED, __HIP_MEMORY_SCOPE_AGENT);
          if (oldr == 7u) {
            #pragma unroll
            for (int gg = 0; gg < 8; ++gg)
              __hip_atomic_store(&gflag[gg * 1024 + k], 1u,
                                 __ATOMIC_RELAXED, __HIP_MEMORY_SCOPE_AGENT);
          }
        }
        __builtin_amdgcn_fence(__ATOMIC_ACQUIRE, "agent");
      }
    }

    // ---- overlap window: deferred out stores + next-step xg prefetch ----
    if (kh == 0 && active && l < 16) {
      const int row = rbase + l;
      if (lay) {
        *(f32x4*)(out + (size_t)row * 524288u + (size_t)(k - 1) * 1024u + bid * 4) = outv;
        if (k == T_)
          *(f32x4*)(out + HS_OFF + 65536 + row * 1024 + bid * 4) = outv;
      } else if (k == T_ - 1) {
        *(f32x4*)(out + HS_OFF + row * 1024 + bid * 4) = outv;
      }
    }
    if (use_xg && lay == 0 && kh == 0 && k + 1 < T_) {
      ushort4 xv = *(const ushort4*)(xg + ((((size_t)(k + 1) * 256 + bid) * 4 + rt) * 64 + l) * 4);
      xgf[0] = bf2f(xv.x); xgf[1] = bf2f(xv.y); xgf[2] = bf2f(xv.z); xgf[3] = bf2f(xv.w);
    }

    // ---- barrier wait (per-group flag line); syncthreads = ordering fence ----
    if (k < T_) {
      if (tid == 0) {
        unsigned spins = 0;
        while (__hip_atomic_load(&gflag[grp * 1024 + k], __ATOMIC_RELAXED, __HIP_MEMORY_SCOPE_AGENT) == 0u) {
          __builtin_amdgcn_s_sleep(1);
          if (++spins > 67108864u) break;   // safety: never wedge the GPU
        }
      }
      __syncthreads();
    }
  }

  // final cell states (rare, scattered is fine)
  if (kh == 0 && (l & 3) == 0) {
    #pragma unroll
    for (int v = 0; v < 4; ++v)
      out[CS_OFF + lay * 65536 + (rbase + (l >> 4) * 4 + v) * 1024 + jg] = cr[v];
  }
}

extern "C" void kernel_launch(void* const* d_in, const int* in_sizes, int n_in,
                              void* d_out, int out_size, void* d_ws, size_t ws_size,
                              hipStream_t stream) {
  const float* x   = (const float*)d_in[0];
  const float* h0  = (const float*)d_in[1];
  const float* c0  = (const float*)d_in[2];
  const float* Wx0 = (const float*)d_in[3];
  const float* Wh0 = (const float*)d_in[4];
  const float* b0  = (const float*)d_in[5];
  const float* Wx1 = (const float*)d_in[6];
  const float* Wh1 = (const float*)d_in[7];
  const float* b1  = (const float*)d_in[8];
  float* out = (float*)d_out;
  char* ws = (char*)d_ws;
  if (ws_size < (size_t)WS_MIN) return;   // workspace too small -> fail loudly
  const int use_xg = (ws_size >= (size_t)WS_BIG) ? 1 : 0;

  unsigned* ctr       = (unsigned*)(ws + WS_CTR);
  unsigned short* wp  = (unsigned short*)(ws + WS_W);
  float* biasP        = (float*)(ws + WS_BIAS);
  unsigned short* xbp = (unsigned short*)(ws + WS_XB);
  unsigned short* h0r = (unsigned short*)(ws + WS_H0);
  unsigned short* h1r = (unsigned short*)(ws + WS_H1);
  unsigned short* xgp = (unsigned short*)(ws + WS_XG);

  (void)hipMemsetAsync(ctr, 0, 69632, stream);
  hipLaunchKernelGGL(kw,    dim3(4096),  dim3(256), 0, stream, Wx0, Wh0, Wx1, Wh1, wp);
  hipLaunchKernelGGL(kx,    dim3(32768), dim3(256), 0, stream, x, xbp);
  hipLaunchKernelGGL(kmisc, dim3(544),   dim3(256), 0, stream, b0, b1, h0, biasP, h0r, h1r);
  if (use_xg)
    hipLaunchKernelGGL(kxg, dim3(2048),  dim3(512), 0, stream, wp, xbp, xgp);

  (void)hipFuncSetAttribute((const void*)klstm, hipFuncAttributeMaxDynamicSharedMemorySize, 75776);
  const float* c0a = c0; const unsigned short* wpa = wp; const float* bpa = biasP;
  const unsigned short* xba = xbp; const unsigned short* xga = xgp;
  unsigned short* h0a = h0r; unsigned short* h1a = h1r;
  unsigned* ca = ctr; float* oa = out; int uxg = use_xg;
  void* args[] = {&c0a, &wpa, &bpa, &xba, &xga, &h0a, &h1a, &ca, &oa, &uxg};
  hipError_t e = hipLaunchCooperativeKernel((const void*)klstm, dim3(NBLK), dim3(TPB),
                                            args, 75776, stream);
  if (e != hipSuccess) {
    hipLaunchKernelGGL(klstm, dim3(NBLK), dim3(TPB), 75776, stream,
                       c0a, wpa, bpa, xba, xga, h0a, h1a, ca, oa, uxg);
  }
}

// Round 12
// 5623.177 us; speedup vs baseline: 1.1686x; 1.1686x over previous
//
#include <hip/hip_runtime.h>

// CustomLSTM on MI355X: persistent cooperative kernel (R10 structure, best
// measured). R12: kxg pre-GEMM eliminated — x[k+1]@Wx0 computed in the
// barrier-wait overlap window each step (partials in regs / 4KB LDS exchange).

#define NBLK 256
#define TPB  512
#define T_   512
#define HS_OFF 33554432   // outputs floats
#define CS_OFF 33685504   // HS_OFF + 2*64*1024

typedef float  f32x4  __attribute__((ext_vector_type(4)));
typedef short  bf16x8 __attribute__((ext_vector_type(8)));

// ---- workspace byte offsets ----
#define WS_CTR  0u              // 69632: gctr[8][1024] | rctr[1024] | gflag[8][1024]
#define WS_W    69632u          // 4 * (4096*1024) bf16 = 32 MiB (permuted, [m][p][k])
#define WS_BIAS 33624064u       // 2*4096 f32
#define WS_XB   33656832u       // [T][B][D] bf16 = 64 MiB
#define WS_H0   100765696u      // ring: 2 * 65536 bf16, layout [oct][row][8]
#define WS_H1   101027840u
#define WS_MIN  101289984u

__device__ __forceinline__ unsigned short f2bf(float f) {
  union { float f; unsigned u; } v; v.f = f;
  return (unsigned short)((v.u + 0x7FFFu + ((v.u >> 16) & 1u)) >> 16);
}
__device__ __forceinline__ float fsig(float x) { return 1.0f / (1.0f + __expf(-x)); }
__device__ __forceinline__ float ftanh(float x) {
  x = fminf(15.0f, fmaxf(-15.0f, x));
  float e = __expf(2.0f * x);
  return (e - 1.0f) / (e + 1.0f);
}

// Permute+transpose+bf16 the 4 weight matrices: out[m][p][k] = bf16(W_m[k][orig(p)]),
// orig(p) = (p&3)*1024 + (p>>2)  (p = 4*j + gate). 64x64 tiles via LDS.
__global__ void kw(const float* __restrict__ Wx0, const float* __restrict__ Wh0,
                   const float* __restrict__ Wx1, const float* __restrict__ Wh1,
                   unsigned short* __restrict__ wp) {
  __shared__ float tile[64][65];
  int tb = blockIdx.x;
  int m  = tb >> 10;
  int kt = (tb >> 6) & 15;
  int nt = tb & 63;
  const float* W = (m == 0) ? Wx0 : (m == 1) ? Wh0 : (m == 2) ? Wx1 : Wh1;
  unsigned short* O = wp + (size_t)m * 4194304u;
  int k0 = kt * 64, n0 = nt * 64;
  int tx = threadIdx.x & 63, tg = threadIdx.x >> 6;
  for (int r = tg; r < 64; r += 4)
    tile[r][tx] = W[(size_t)(k0 + r) * 4096 + n0 + tx];
  __syncthreads();
  for (int r = tg; r < 64; r += 4) {
    int n = n0 + r;
    int p = ((n & 1023) << 2) | (n >> 10);
    O[(size_t)p * 1024 + k0 + tx] = f2bf(tile[tx][r]);
  }
}

// x [B][T][D] f32 -> xb [T*B][D] bf16 (row = t*64+b)
__global__ void kx(const float* __restrict__ x, unsigned short* __restrict__ xb) {
  int row = blockIdx.x;
  int t = row >> 6, b = row & 63;
  const float4* src = (const float4*)(x + ((size_t)b * 512 + t) * 1024);
  float4 f = src[threadIdx.x];
  ushort4 o; o.x = f2bf(f.x); o.y = f2bf(f.y); o.z = f2bf(f.z); o.w = f2bf(f.w);
  ((ushort4*)(xb + (size_t)row * 1024))[threadIdx.x] = o;
}

// bias permute + prime ring slot 1 with initial h states (bf16, [oct][row][8])
__global__ void kmisc(const float* __restrict__ b0, const float* __restrict__ b1,
                      const float* __restrict__ h0in,
                      float* __restrict__ biasP,
                      unsigned short* __restrict__ h0r, unsigned short* __restrict__ h1r) {
  int idx = blockIdx.x * 256 + threadIdx.x;
  if (idx < 8192) {
    int layer = idx >> 12, p = idx & 4095;
    int orig = (p & 3) * 1024 + (p >> 2);
    biasP[idx] = (layer ? b1 : b0)[orig];
  } else if (idx < 139264) {
    int e = idx - 8192;
    int layer = e >> 16, o = e & 65535;
    int row = o >> 10, col = o & 1023;
    unsigned short v = f2bf(h0in[layer * 65536 + o]);
    int dst = 65536 + (col >> 3) * 512 + row * 8 + (col & 7);
    if (layer) h1r[dst] = v; else h0r[dst] = v;
  }
}

// Persistent cooperative kernel. 256 blocks x 512 threads (8 waves).
// Wave w: rows 16*(w&3), K-half (w>>2)*512, finalizes layer (w>>2).
// x[k+1]@Wx0 computed in overlap window; partial exchange via xred LDS.
__global__ void __launch_bounds__(TPB)
klstm(const float* __restrict__ c0_in,
      const unsigned short* __restrict__ wp,
      const float* __restrict__ biasP,
      const unsigned short* __restrict__ xb,
      unsigned short* __restrict__ h0ring,
      unsigned short* __restrict__ h1ring,
      unsigned* __restrict__ ctrbase,
      float* __restrict__ out) {
  extern __shared__ char smem[];           // 32K Wx0 | 32K Wx1 | 8K red | 2K lh | 4K xred
  float* red  = (float*)(smem + 65536);
  float* lhb  = (float*)(smem + 73728);
  float* xred = (float*)(smem + 75776);
  unsigned* gctr  = ctrbase;               // [8][1024]
  unsigned* rctr  = ctrbase + 8192;        // [1024]
  unsigned* gflag = ctrbase + 9216;        // [8][1024]
  const int tid = threadIdx.x;
  const int w   = tid >> 6;
  const int l   = tid & 63;
  const int bid = blockIdx.x;
  const int n0  = bid * 16;
  const int layer = w >> 2;
  const int rbase = (w & 3) * 16;
  const int khalf = (w >> 2) * 512;
  const int grp   = bid >> 5;
  float* lh = lhb + w * 64;                // [16 rows][4 cols] f32 per wave

  // stage Wx0 (m=0) at 0 and Wx1 (m=2) at 32K into LDS, XOR-swizzled
  for (int m = 0; m < 4; m += 2) {
    const char* src = (const char*)(wp + (size_t)m * 4194304u + (size_t)n0 * 1024u);
    char* dst = smem + (m >> 1) * 32768;
    for (int i = tid; i < 2048; i += TPB) {
      int sb = i << 4;
      int c  = sb >> 11;
      int kb = sb & 2047;
      *(uint4*)(dst + (c << 11) + (kb ^ ((c & 7) << 4))) = *(const uint4*)(src + sb);
    }
  }

  // pin Wh0 / Wh1 fragments (16 cols x this wave's K-half)
  bf16x8 wh0f[16], wh1f[16];
  {
    const unsigned short* p0 = wp + 4194304u + (size_t)(n0 + (l & 15)) * 1024u + khalf + (l >> 4) * 8;
    const unsigned short* p1 = wp + 3u * 4194304u + (size_t)(n0 + (l & 15)) * 1024u + khalf + (l >> 4) * 8;
    #pragma unroll
    for (int ks = 0; ks < 16; ++ks) {
      wh0f[ks] = *(const bf16x8*)(p0 + ks * 32);
      wh1f[ks] = *(const bf16x8*)(p1 + ks * 32);
    }
  }

  const int jg = bid * 4 + ((l & 15) >> 2);   // global h column (gate finalize)
  const float biasv = biasP[layer * 4096 + n0 + (l & 15)];
  const int qb = l & ~3;

  float cr[4];
  #pragma unroll
  for (int v = 0; v < 4; ++v)
    cr[v] = c0_in[layer * 65536 + (rbase + (l >> 4) * 4 + v) * 1024 + jg];

  const int ae0  = (rbase + (l & 15)) * 1024 + khalf + (l >> 4) * 8;  // xb (row-major)
  const int hbase = ((khalf >> 3) + (l >> 4)) * 512 + (rbase + (l & 15)) * 8;
  const int lb0  = (l & 15) << 11;
  const int kb2  = khalf * 2 + (l >> 4) * 16;
  const int swz  = (l & 7) << 4;
  const int hsto = (bid >> 1) * 512 + 4 * (bid & 1);

  __syncthreads();                         // Wx staging visible

  // prologue: x[0]@Wx0 slice for this wave
  f32x4 xacc = {0.f, 0.f, 0.f, 0.f};
  {
    #pragma unroll
    for (int kk = 0; kk < 16; ++kk) {
      bf16x8 ax = *(const bf16x8*)(xb + ae0 + kk * 32);
      bf16x8 b  = *(const bf16x8*)(smem + lb0 + ((kb2 + kk * 64) ^ swz));
      xacc = __builtin_amdgcn_mfma_f32_16x16x32_bf16(ax, b, xacc, 0, 0, 0);
    }
    if (w >= 4) {
      float* xr = xred + (size_t)(w & 3) * 256 + (size_t)l * 4;
      #pragma unroll
      for (int v = 0; v < 4; ++v) xr[v] = xacc[v];
    }
  }
  __syncthreads();

  for (int k = 0; k <= T_; ++k) {
    #pragma unroll
    for (int ks = 0; ks < 16; ++ks) {
      asm volatile("" :: "v"(wh0f[ks]));
      asm volatile("" :: "v"(wh1f[ks]));
    }

    const unsigned short* h0p = h0ring + ((k + 1) & 1) * 65536;
    const unsigned short* h1p = h1ring + (k & 1) * 65536;

    f32x4 acc0  = {0.f, 0.f, 0.f, 0.f};
    f32x4 acc1a = {0.f, 0.f, 0.f, 0.f};
    f32x4 acc1b = {0.f, 0.f, 0.f, 0.f};
    #pragma unroll
    for (int kk = 0; kk < 16; ++kk) {
      bf16x8 ah0 = *(const bf16x8*)(h0p + hbase + kk * 2048);
      bf16x8 ah1 = *(const bf16x8*)(h1p + hbase + kk * 2048);
      bf16x8 bx1 = *(const bf16x8*)(smem + 32768 + lb0 + ((kb2 + kk * 64) ^ swz));
      acc0  = __builtin_amdgcn_mfma_f32_16x16x32_bf16(ah0, wh0f[kk], acc0, 0, 0, 0);
      acc1a = __builtin_amdgcn_mfma_f32_16x16x32_bf16(ah0, bx1, acc1a, 0, 0, 0);
      acc1b = __builtin_amdgcn_mfma_f32_16x16x32_bf16(ah1, wh1f[kk], acc1b, 0, 0, 0);
    }

    { // publish the other layer's partial for the partner wave
      float* rb = red + (size_t)(w * 64 + l) * 4;
      f32x4 other = layer ? acc0 : (acc1a + acc1b);
      #pragma unroll
      for (int v = 0; v < 4; ++v) rb[v] = other[v];
    }
    __syncthreads();

    f32x4 g = layer ? (acc1a + acc1b) : acc0;
    {
      const int pw = layer ? (w - 4) : (w + 4);
      const float* rb = red + (size_t)(pw * 64 + l) * 4;
      #pragma unroll
      for (int v = 0; v < 4; ++v) g[v] += rb[v];
    }
    if (w < 4) {   // + x@Wx0: own half (regs) + partner half (xred)
      const float* xr = xred + (size_t)w * 256 + (size_t)l * 4;
      #pragma unroll
      for (int v = 0; v < 4; ++v) g[v] += xacc[v] + xr[v];
    }

    const bool active = layer ? (k >= 1) : (k < T_);
    f32x4 outv = {0.f, 0.f, 0.f, 0.f};
    if (active) {
      unsigned short* hw = layer ? (h1ring + ((k + 1) & 1) * 65536)
                                 : (h0ring + (k & 1) * 65536);
      #pragma unroll
      for (int v = 0; v < 4; ++v) {
        float gv = g[v] + biasv;
        float gi = __shfl(gv, qb);
        float gf = __shfl(gv, qb | 1);
        float gn = __shfl(gv, qb | 2);
        float go = __shfl(gv, qb | 3);
        float i_ = fsig(gi), f_ = fsig(gf), n_ = ftanh(gn), o_ = fsig(go);
        float c = f_ * cr[v] + i_ * n_;
        cr[v] = c;
        float h = o_ * ftanh(c);
        if ((l & 3) == 0)
          lh[((l >> 4) * 4 + v) * 4 + ((l & 15) >> 2)] = h;   // repack tile
      }
      if (l < 16) {   // same-wave read-back: coalesced 8B agent store
        f32x4 h4 = *(f32x4*)(lh + l * 4);
        outv = h4;
        ushort4 u4;
        u4.x = f2bf(h4[0]); u4.y = f2bf(h4[1]); u4.z = f2bf(h4[2]); u4.w = f2bf(h4[3]);
        union { ushort4 s; unsigned long long q; } pk; pk.s = u4;
        __hip_atomic_store((unsigned long long*)(hw + hsto + (rbase + l) * 8), pk.q,
                           __ATOMIC_RELAXED, __HIP_MEMORY_SCOPE_AGENT);
      }
    }

    // ---- barrier arrival + early acquire-inv (off the critical path) ----
    if (k < T_) {
      __syncthreads();                      // drain h stores block-wide
      if (tid == 0) {
        unsigned old = __hip_atomic_fetch_add(&gctr[grp * 1024 + k], 1u,
                                              __ATOMIC_RELAXED, __HIP_MEMORY_SCOPE_AGENT);
        if (old == 31u) {
          unsigned oldr = __hip_atomic_fetch_add(&rctr[k], 1u,
                                                 __ATOMIC_RELAXED, __HIP_MEMORY_SCOPE_AGENT);
          if (oldr == 7u) {
            #pragma unroll
            for (int gg = 0; gg < 8; ++gg)
              __hip_atomic_store(&gflag[gg * 1024 + k], 1u,
                                 __ATOMIC_RELAXED, __HIP_MEMORY_SCOPE_AGENT);
          }
        }
        __builtin_amdgcn_fence(__ATOMIC_ACQUIRE, "agent");
      }
    }

    // ---- overlap window: out stores + x[k+1]@Wx0 slice (dead-time work) ----
    if (active && l < 16) {
      const int row = rbase + l;
      if (layer) {
        *(f32x4*)(out + (size_t)row * 524288u + (size_t)(k - 1) * 1024u + bid * 4) = outv;
        if (k == T_)
          *(f32x4*)(out + HS_OFF + 65536 + row * 1024 + bid * 4) = outv;
      } else if (k == T_ - 1) {
        *(f32x4*)(out + HS_OFF + row * 1024 + bid * 4) = outv;
      }
    }
    if (k + 1 < T_) {
      const unsigned short* xt = xb + (size_t)(k + 1) * 65536u;
      f32x4 xa = {0.f, 0.f, 0.f, 0.f};
      #pragma unroll
      for (int kk = 0; kk < 16; ++kk) {
        bf16x8 ax = *(const bf16x8*)(xt + ae0 + kk * 32);
        bf16x8 b  = *(const bf16x8*)(smem + lb0 + ((kb2 + kk * 64) ^ swz));
        xa = __builtin_amdgcn_mfma_f32_16x16x32_bf16(ax, b, xa, 0, 0, 0);
      }
      if (w >= 4) {   // publish K-half-1 partial; consumed at step k+1 finalize
        float* xr = xred + (size_t)(w & 3) * 256 + (size_t)l * 4;
        #pragma unroll
        for (int v = 0; v < 4; ++v) xr[v] = xa[v];
      } else {
        xacc = xa;
      }
    }

    // ---- barrier wait (per-group flag line); syncthreads = ordering fence ----
    if (k < T_) {
      if (tid == 0) {
        unsigned spins = 0;
        while (__hip_atomic_load(&gflag[grp * 1024 + k], __ATOMIC_RELAXED, __HIP_MEMORY_SCOPE_AGENT) == 0u) {
          __builtin_amdgcn_s_sleep(1);
          if (++spins > 67108864u) break;   // safety: never wedge the GPU
        }
      }
      __syncthreads();
    }
  }

  // final cell states (rare, scattered is fine)
  if ((l & 3) == 0) {
    #pragma unroll
    for (int v = 0; v < 4; ++v)
      out[CS_OFF + layer * 65536 + (rbase + (l >> 4) * 4 + v) * 1024 + jg] = cr[v];
  }
}

extern "C" void kernel_launch(void* const* d_in, const int* in_sizes, int n_in,
                              void* d_out, int out_size, void* d_ws, size_t ws_size,
                              hipStream_t stream) {
  const float* x   = (const float*)d_in[0];
  const float* h0  = (const float*)d_in[1];
  const float* c0  = (const float*)d_in[2];
  const float* Wx0 = (const float*)d_in[3];
  const float* Wh0 = (const float*)d_in[4];
  const float* b0  = (const float*)d_in[5];
  const float* Wx1 = (const float*)d_in[6];
  const float* Wh1 = (const float*)d_in[7];
  const float* b1  = (const float*)d_in[8];
  float* out = (float*)d_out;
  char* ws = (char*)d_ws;
  if (ws_size < (size_t)WS_MIN) return;   // workspace too small -> fail loudly

  unsigned* ctr       = (unsigned*)(ws + WS_CTR);
  unsigned short* wp  = (unsigned short*)(ws + WS_W);
  float* biasP        = (float*)(ws + WS_BIAS);
  unsigned short* xbp = (unsigned short*)(ws + WS_XB);
  unsigned short* h0r = (unsigned short*)(ws + WS_H0);
  unsigned short* h1r = (unsigned short*)(ws + WS_H1);

  (void)hipMemsetAsync(ctr, 0, 69632, stream);
  hipLaunchKernelGGL(kw,    dim3(4096),  dim3(256), 0, stream, Wx0, Wh0, Wx1, Wh1, wp);
  hipLaunchKernelGGL(kx,    dim3(32768), dim3(256), 0, stream, x, xbp);
  hipLaunchKernelGGL(kmisc, dim3(544),   dim3(256), 0, stream, b0, b1, h0, biasP, h0r, h1r);

  (void)hipFuncSetAttribute((const void*)klstm, hipFuncAttributeMaxDynamicSharedMemorySize, 79872);
  const float* c0a = c0; const unsigned short* wpa = wp; const float* bpa = biasP;
  const unsigned short* xba = xbp;
  unsigned short* h0a = h0r; unsigned short* h1a = h1r;
  unsigned* ca = ctr; float* oa = out;
  void* args[] = {&c0a, &wpa, &bpa, &xba, &h0a, &h1a, &ca, &oa};
  hipError_t e = hipLaunchCooperativeKernel((const void*)klstm, dim3(NBLK), dim3(TPB),
                                            args, 79872, stream);
  if (e != hipSuccess) {
    hipLaunchKernelGGL(klstm, dim3(NBLK), dim3(TPB), 79872, stream,
                       c0a, wpa, bpa, xba, h0a, h1a, ca, oa);
  }
}

// Round 13
// 5220.451 us; speedup vs baseline: 1.2587x; 1.0771x over previous
//
#include <hip/hip_runtime.h>

// CustomLSTM on MI355X: persistent cooperative kernel (R12 skeleton).
// R13: Wh0/Wh1 staged in LDS (were silently re-read from global every step),
// explicit h-fragment preload burst (128 VGPR), 16x16 arrival tree.

#define NBLK 256
#define TPB  512
#define T_   512
#define HS_OFF 33554432   // outputs floats
#define CS_OFF 33685504   // HS_OFF + 2*64*1024

typedef float  f32x4  __attribute__((ext_vector_type(4)));
typedef short  bf16x8 __attribute__((ext_vector_type(8)));

// ---- workspace byte offsets ----
#define WS_CTR  0u              // 139264: gctr[16][1024] | rctr[1024] | gflag[16][1024]
#define WS_W    139264u         // 4 * (4096*1024) bf16 = 32 MiB (permuted, [m][p][k])
#define WS_BIAS 33693696u       // 2*4096 f32
#define WS_XB   33726464u       // [T][B][D] bf16 = 64 MiB
#define WS_H0   100835328u      // ring: 2 * 65536 bf16, layout [oct][row][8]
#define WS_H1   101097472u
#define WS_MIN  101359616u

__device__ __forceinline__ unsigned short f2bf(float f) {
  union { float f; unsigned u; } v; v.f = f;
  return (unsigned short)((v.u + 0x7FFFu + ((v.u >> 16) & 1u)) >> 16);
}
__device__ __forceinline__ float fsig(float x) { return 1.0f / (1.0f + __expf(-x)); }
__device__ __forceinline__ float ftanh(float x) {
  x = fminf(15.0f, fmaxf(-15.0f, x));
  float e = __expf(2.0f * x);
  return (e - 1.0f) / (e + 1.0f);
}

// Permute+transpose+bf16 the 4 weight matrices: out[m][p][k] = bf16(W_m[k][orig(p)]),
// orig(p) = (p&3)*1024 + (p>>2)  (p = 4*j + gate). 64x64 tiles via LDS.
__global__ void kw(const float* __restrict__ Wx0, const float* __restrict__ Wh0,
                   const float* __restrict__ Wx1, const float* __restrict__ Wh1,
                   unsigned short* __restrict__ wp) {
  __shared__ float tile[64][65];
  int tb = blockIdx.x;
  int m  = tb >> 10;
  int kt = (tb >> 6) & 15;
  int nt = tb & 63;
  const float* W = (m == 0) ? Wx0 : (m == 1) ? Wh0 : (m == 2) ? Wx1 : Wh1;
  unsigned short* O = wp + (size_t)m * 4194304u;
  int k0 = kt * 64, n0 = nt * 64;
  int tx = threadIdx.x & 63, tg = threadIdx.x >> 6;
  for (int r = tg; r < 64; r += 4)
    tile[r][tx] = W[(size_t)(k0 + r) * 4096 + n0 + tx];
  __syncthreads();
  for (int r = tg; r < 64; r += 4) {
    int n = n0 + r;
    int p = ((n & 1023) << 2) | (n >> 10);
    O[(size_t)p * 1024 + k0 + tx] = f2bf(tile[tx][r]);
  }
}

// x [B][T][D] f32 -> xb [T*B][D] bf16 (row = t*64+b)
__global__ void kx(const float* __restrict__ x, unsigned short* __restrict__ xb) {
  int row = blockIdx.x;
  int t = row >> 6, b = row & 63;
  const float4* src = (const float4*)(x + ((size_t)b * 512 + t) * 1024);
  float4 f = src[threadIdx.x];
  ushort4 o; o.x = f2bf(f.x); o.y = f2bf(f.y); o.z = f2bf(f.z); o.w = f2bf(f.w);
  ((ushort4*)(xb + (size_t)row * 1024))[threadIdx.x] = o;
}

// bias permute + prime ring slot 1 with initial h states (bf16, [oct][row][8])
__global__ void kmisc(const float* __restrict__ b0, const float* __restrict__ b1,
                      const float* __restrict__ h0in,
                      float* __restrict__ biasP,
                      unsigned short* __restrict__ h0r, unsigned short* __restrict__ h1r) {
  int idx = blockIdx.x * 256 + threadIdx.x;
  if (idx < 8192) {
    int layer = idx >> 12, p = idx & 4095;
    int orig = (p & 3) * 1024 + (p >> 2);
    biasP[idx] = (layer ? b1 : b0)[orig];
  } else if (idx < 139264) {
    int e = idx - 8192;
    int layer = e >> 16, o = e & 65535;
    int row = o >> 10, col = o & 1023;
    unsigned short v = f2bf(h0in[layer * 65536 + o]);
    int dst = 65536 + (col >> 3) * 512 + row * 8 + (col & 7);
    if (layer) h1r[dst] = v; else h0r[dst] = v;
  }
}

// Persistent cooperative kernel. 256 blocks x 512 threads (8 waves).
// Wave w: rows 16*(w&3), K-half (w>>2)*512, finalizes layer (w>>2).
// All 4 weight slices in LDS; h fragments preloaded in one burst per step;
// x[k+1]@Wx0 computed in the barrier-wait overlap window.
__global__ void __launch_bounds__(TPB, 2)
klstm(const float* __restrict__ c0_in,
      const unsigned short* __restrict__ wp,
      const float* __restrict__ biasP,
      const unsigned short* __restrict__ xb,
      unsigned short* __restrict__ h0ring,
      unsigned short* __restrict__ h1ring,
      unsigned* __restrict__ ctrbase,
      float* __restrict__ out) {
  extern __shared__ char smem[];   // 32K Wx0 | 32K Wx1 | 32K Wh0 | 32K Wh1 | 8K red | 2K lh | 4K xred
  float* red  = (float*)(smem + 131072);
  float* lhb  = (float*)(smem + 139264);
  float* xred = (float*)(smem + 141312);
  unsigned* gctr  = ctrbase;               // [16][1024]
  unsigned* rctr  = ctrbase + 16384;       // [1024]
  unsigned* gflag = ctrbase + 17408;       // [16][1024]
  const int tid = threadIdx.x;
  const int w   = tid >> 6;
  const int l   = tid & 63;
  const int bid = blockIdx.x;
  const int n0  = bid * 16;
  const int layer = w >> 2;
  const int rbase = (w & 3) * 16;
  const int khalf = (w >> 2) * 512;
  const int grp   = bid >> 4;              // 16 groups of 16 blocks
  float* lh = lhb + w * 64;                // [16 rows][4 cols] f32 per wave

  // stage all 4 weight slices into LDS: slot0=Wx0(m0) slot1=Wx1(m2) slot2=Wh0(m1) slot3=Wh1(m3)
  {
    const int msrc[4] = {0, 2, 1, 3};
    for (int s = 0; s < 4; ++s) {
      const char* src = (const char*)(wp + (size_t)msrc[s] * 4194304u + (size_t)n0 * 1024u);
      char* dst = smem + s * 32768;
      for (int i = tid; i < 2048; i += TPB) {
        int sb = i << 4;
        int c  = sb >> 11;
        int kb = sb & 2047;
        *(uint4*)(dst + (c << 11) + (kb ^ ((c & 7) << 4))) = *(const uint4*)(src + sb);
      }
    }
  }

  const int jg = bid * 4 + ((l & 15) >> 2);   // global h column (gate finalize)
  const float biasv = biasP[layer * 4096 + n0 + (l & 15)];
  const int qb = l & ~3;

  float cr[4];
  #pragma unroll
  for (int v = 0; v < 4; ++v)
    cr[v] = c0_in[layer * 65536 + (rbase + (l >> 4) * 4 + v) * 1024 + jg];

  const int ae0  = (rbase + (l & 15)) * 1024 + khalf + (l >> 4) * 8;  // xb (row-major)
  const int hbase = ((khalf >> 3) + (l >> 4)) * 512 + (rbase + (l & 15)) * 8;
  const int lb0  = (l & 15) << 11;
  const int kb2  = khalf * 2 + (l >> 4) * 16;
  const int swz  = (l & 7) << 4;
  const int hsto = (bid >> 1) * 512 + 4 * (bid & 1);

  __syncthreads();                         // weight staging visible

  // prologue: x[0]@Wx0 slice for this wave
  f32x4 xacc = {0.f, 0.f, 0.f, 0.f};
  {
    #pragma unroll
    for (int kk = 0; kk < 16; ++kk) {
      bf16x8 ax = *(const bf16x8*)(xb + ae0 + kk * 32);
      bf16x8 b  = *(const bf16x8*)(smem + lb0 + ((kb2 + kk * 64) ^ swz));
      xacc = __builtin_amdgcn_mfma_f32_16x16x32_bf16(ax, b, xacc, 0, 0, 0);
    }
    if (w >= 4) {
      float* xr = xred + (size_t)(w & 3) * 256 + (size_t)l * 4;
      #pragma unroll
      for (int v = 0; v < 4; ++v) xr[v] = xacc[v];
    }
  }
  __syncthreads();

  for (int k = 0; k <= T_; ++k) {
    const unsigned short* h0p = h0ring + ((k + 1) & 1) * 65536;
    const unsigned short* h1p = h1ring + (k & 1) * 65536;

    // ---- preload ALL h fragments in one burst (the only post-flag global reads) ----
    bf16x8 hf0[16], hf1[16];
    #pragma unroll
    for (int kk = 0; kk < 16; ++kk) {
      hf0[kk] = *(const bf16x8*)(h0p + hbase + kk * 2048);
      hf1[kk] = *(const bf16x8*)(h1p + hbase + kk * 2048);
    }

    f32x4 acc0  = {0.f, 0.f, 0.f, 0.f};
    f32x4 acc1a = {0.f, 0.f, 0.f, 0.f};
    f32x4 acc1b = {0.f, 0.f, 0.f, 0.f};
    #pragma unroll
    for (int kk = 0; kk < 16; ++kk) {
      const int bo = lb0 + ((kb2 + kk * 64) ^ swz);
      bf16x8 bh0 = *(const bf16x8*)(smem + 65536 + bo);
      bf16x8 bx1 = *(const bf16x8*)(smem + 32768 + bo);
      bf16x8 bh1 = *(const bf16x8*)(smem + 98304 + bo);
      acc0  = __builtin_amdgcn_mfma_f32_16x16x32_bf16(hf0[kk], bh0, acc0, 0, 0, 0);
      acc1a = __builtin_amdgcn_mfma_f32_16x16x32_bf16(hf0[kk], bx1, acc1a, 0, 0, 0);
      acc1b = __builtin_amdgcn_mfma_f32_16x16x32_bf16(hf1[kk], bh1, acc1b, 0, 0, 0);
    }

    { // publish the other layer's partial for the partner wave
      float* rb = red + (size_t)(w * 64 + l) * 4;
      f32x4 other = layer ? acc0 : (acc1a + acc1b);
      #pragma unroll
      for (int v = 0; v < 4; ++v) rb[v] = other[v];
    }
    __syncthreads();

    f32x4 g = layer ? (acc1a + acc1b) : acc0;
    {
      const int pw = layer ? (w - 4) : (w + 4);
      const float* rb = red + (size_t)(pw * 64 + l) * 4;
      #pragma unroll
      for (int v = 0; v < 4; ++v) g[v] += rb[v];
    }
    if (w < 4) {   // + x@Wx0: own half (regs) + partner half (xred)
      const float* xr = xred + (size_t)w * 256 + (size_t)l * 4;
      #pragma unroll
      for (int v = 0; v < 4; ++v) g[v] += xacc[v] + xr[v];
    }

    const bool active = layer ? (k >= 1) : (k < T_);
    f32x4 outv = {0.f, 0.f, 0.f, 0.f};
    if (active) {
      unsigned short* hw = layer ? (h1ring + ((k + 1) & 1) * 65536)
                                 : (h0ring + (k & 1) * 65536);
      #pragma unroll
      for (int v = 0; v < 4; ++v) {
        float gv = g[v] + biasv;
        float gi = __shfl(gv, qb);
        float gf = __shfl(gv, qb | 1);
        float gn = __shfl(gv, qb | 2);
        float go = __shfl(gv, qb | 3);
        float i_ = fsig(gi), f_ = fsig(gf), n_ = ftanh(gn), o_ = fsig(go);
        float c = f_ * cr[v] + i_ * n_;
        cr[v] = c;
        float h = o_ * ftanh(c);
        if ((l & 3) == 0)
          lh[((l >> 4) * 4 + v) * 4 + ((l & 15) >> 2)] = h;   // repack tile
      }
      if (l < 16) {   // same-wave read-back: coalesced 8B agent store
        f32x4 h4 = *(f32x4*)(lh + l * 4);
        outv = h4;
        ushort4 u4;
        u4.x = f2bf(h4[0]); u4.y = f2bf(h4[1]); u4.z = f2bf(h4[2]); u4.w = f2bf(h4[3]);
        union { ushort4 s; unsigned long long q; } pk; pk.s = u4;
        __hip_atomic_store((unsigned long long*)(hw + hsto + (rbase + l) * 8), pk.q,
                           __ATOMIC_RELAXED, __HIP_MEMORY_SCOPE_AGENT);
      }
    }

    // ---- barrier arrival (16x16 tree) + early acquire-inv ----
    if (k < T_) {
      __syncthreads();                      // drain h stores block-wide
      if (tid == 0) {
        unsigned old = __hip_atomic_fetch_add(&gctr[grp * 1024 + k], 1u,
                                              __ATOMIC_RELAXED, __HIP_MEMORY_SCOPE_AGENT);
        if (old == 15u) {
          unsigned oldr = __hip_atomic_fetch_add(&rctr[k], 1u,
                                                 __ATOMIC_RELAXED, __HIP_MEMORY_SCOPE_AGENT);
          if (oldr == 15u) {
            #pragma unroll
            for (int gg = 0; gg < 16; ++gg)
              __hip_atomic_store(&gflag[gg * 1024 + k], 1u,
                                 __ATOMIC_RELAXED, __HIP_MEMORY_SCOPE_AGENT);
          }
        }
        __builtin_amdgcn_fence(__ATOMIC_ACQUIRE, "agent");
      }
    }

    // ---- overlap window: out stores + x[k+1]@Wx0 slice (dead-time work) ----
    if (active && l < 16) {
      const int row = rbase + l;
      if (layer) {
        *(f32x4*)(out + (size_t)row * 524288u + (size_t)(k - 1) * 1024u + bid * 4) = outv;
        if (k == T_)
          *(f32x4*)(out + HS_OFF + 65536 + row * 1024 + bid * 4) = outv;
      } else if (k == T_ - 1) {
        *(f32x4*)(out + HS_OFF + row * 1024 + bid * 4) = outv;
      }
    }
    if (k + 1 < T_) {
      const unsigned short* xt = xb + (size_t)(k + 1) * 65536u;
      f32x4 xa = {0.f, 0.f, 0.f, 0.f};
      #pragma unroll
      for (int kk = 0; kk < 16; ++kk) {
        bf16x8 ax = *(const bf16x8*)(xt + ae0 + kk * 32);
        bf16x8 b  = *(const bf16x8*)(smem + lb0 + ((kb2 + kk * 64) ^ swz));
        xa = __builtin_amdgcn_mfma_f32_16x16x32_bf16(ax, b, xa, 0, 0, 0);
      }
      if (w >= 4) {   // publish K-half-1 partial; consumed at step k+1 finalize
        float* xr = xred + (size_t)(w & 3) * 256 + (size_t)l * 4;
        #pragma unroll
        for (int v = 0; v < 4; ++v) xr[v] = xa[v];
      } else {
        xacc = xa;
      }
    }

    // ---- barrier wait (per-group flag line); syncthreads = ordering fence ----
    if (k < T_) {
      if (tid == 0) {
        unsigned spins = 0;
        while (__hip_atomic_load(&gflag[grp * 1024 + k], __ATOMIC_RELAXED, __HIP_MEMORY_SCOPE_AGENT) == 0u) {
          __builtin_amdgcn_s_sleep(1);
          if (++spins > 67108864u) break;   // safety: never wedge the GPU
        }
      }
      __syncthreads();
    }
  }

  // final cell states (rare, scattered is fine)
  if ((l & 3) == 0) {
    #pragma unroll
    for (int v = 0; v < 4; ++v)
      out[CS_OFF + layer * 65536 + (rbase + (l >> 4) * 4 + v) * 1024 + jg] = cr[v];
  }
}

extern "C" void kernel_launch(void* const* d_in, const int* in_sizes, int n_in,
                              void* d_out, int out_size, void* d_ws, size_t ws_size,
                              hipStream_t stream) {
  const float* x   = (const float*)d_in[0];
  const float* h0  = (const float*)d_in[1];
  const float* c0  = (const float*)d_in[2];
  const float* Wx0 = (const float*)d_in[3];
  const float* Wh0 = (const float*)d_in[4];
  const float* b0  = (const float*)d_in[5];
  const float* Wx1 = (const float*)d_in[6];
  const float* Wh1 = (const float*)d_in[7];
  const float* b1  = (const float*)d_in[8];
  float* out = (float*)d_out;
  char* ws = (char*)d_ws;
  if (ws_size < (size_t)WS_MIN) return;   // workspace too small -> fail loudly

  unsigned* ctr       = (unsigned*)(ws + WS_CTR);
  unsigned short* wp  = (unsigned short*)(ws + WS_W);
  float* biasP        = (float*)(ws + WS_BIAS);
  unsigned short* xbp = (unsigned short*)(ws + WS_XB);
  unsigned short* h0r = (unsigned short*)(ws + WS_H0);
  unsigned short* h1r = (unsigned short*)(ws + WS_H1);

  (void)hipMemsetAsync(ctr, 0, 139264, stream);
  hipLaunchKernelGGL(kw,    dim3(4096),  dim3(256), 0, stream, Wx0, Wh0, Wx1, Wh1, wp);
  hipLaunchKernelGGL(kx,    dim3(32768), dim3(256), 0, stream, x, xbp);
  hipLaunchKernelGGL(kmisc, dim3(544),   dim3(256), 0, stream, b0, b1, h0, biasP, h0r, h1r);

  (void)hipFuncSetAttribute((const void*)klstm, hipFuncAttributeMaxDynamicSharedMemorySize, 145408);
  const float* c0a = c0; const unsigned short* wpa = wp; const float* bpa = biasP;
  const unsigned short* xba = xbp;
  unsigned short* h0a = h0r; unsigned short* h1a = h1r;
  unsigned* ca = ctr; float* oa = out;
  void* args[] = {&c0a, &wpa, &bpa, &xba, &h0a, &h1a, &ca, &oa};
  hipError_t e = hipLaunchCooperativeKernel((const void*)klstm, dim3(NBLK), dim3(TPB),
                                            args, 145408, stream);
  if (e != hipSuccess) {
    hipLaunchKernelGGL(klstm, dim3(NBLK), dim3(TPB), 145408, stream,
                       c0a, wpa, bpa, xba, h0a, h1a, ca, oa);
  }
}